// Round 7
// baseline (1525.408 us; speedup 1.0000x reference)
//
#include <hip/hip_runtime.h>

// BinaryTreeLSTM — round 7: single persistent kernel, dataflow flags.
//  * 768 blocks (3/CU guaranteed: LDS 48KB, launch_bounds(256,3)). Block id ->
//    by = bid&7 (64-col gate-major B slice, register-local i,f,g,o),
//    stripe = bid>>3 (row-block stripe, stride 96).
//  * B slice DMA'd to LDS ONCE for all 18 levels (global_load_lds w=16).
//  * Levels 17..0 walked inside the kernel. Tile (level d, rb) = rows
//    [256rb, 256rb+256). Consumer polls flags[d+1][2rb],[2rb+1] == 8 (all 8
//    by-producers of the child tiles), produces flags[d][rb]. No grid
//    barriers, no per-level launches; blocks flow through levels.
//  * emb read fp32 in-kernel (cvt in reg; no separate cvt pass).
//  * h fp16 per-level buffers, c fp32 packed even-rows only; per-level
//    buffers (no ping-pong) -> no WAR hazard across overlapping levels.
//  * K-loop: register A-ring depth 3, fully unrolled (template NCH), LDS B.

typedef _Float16 f16;
typedef f16 f16x8 __attribute__((ext_vector_type(8)));
typedef float f32x4 __attribute__((ext_vector_type(4)));

#define LOG2E 1.44269504f
#define NSTRIPE 96

__device__ __forceinline__ float sigf(float x) {
    return __builtin_amdgcn_rcpf(1.f + __builtin_amdgcn_exp2f(-x * LOG2E));
}
__device__ __forceinline__ float tanh_fast(float x) {
    return 1.f - 2.f * __builtin_amdgcn_rcpf(1.f + __builtin_amdgcn_exp2f(2.f * x * LOG2E));
}

__device__ __forceinline__ void load_lds_16(const void* g, void* l) {
    __builtin_amdgcn_global_load_lds(
        (const __attribute__((address_space(1))) unsigned int*)g,
        (__attribute__((address_space(3))) unsigned int*)l, 16, 0, 0);
}

// Bp layout: [by(8)][kci(12)][kq(4)][c(64)][k8(8)] fp16, c = g*16 + jl,
// orig row = g*256 + by*16 + jl, orig k = kci*32 + kq*8 + k8.
// Also zeroes the 18*512 flag array (ws is 0xAA-poisoned before each call).
__global__ __launch_bounds__(256) void pack_weights(
    const float* __restrict__ W_ih, const float* __restrict__ W_hh,
    const float* __restrict__ b_ih, const float* __restrict__ b_hh,
    f16* __restrict__ Bp, float* __restrict__ biasP, unsigned* __restrict__ flags)
{
    int idx = blockIdx.x * 256 + threadIdx.x;
    if (idx < 196608) {
        int by = idx / 24576;
        int r = idx - by * 24576;
        int kci = r / 2048;
        int r2 = r & 2047;
        int kq = r2 >> 9;
        int r3 = r2 & 511;
        int c = r3 >> 3;
        int k8 = r3 & 7;
        int g = c >> 4, jl = c & 15;
        int rOrig = g * 256 + by * 16 + jl;
        int kk = kci * 32 + kq * 8 + k8;
        float w = (kk < 128) ? W_ih[(size_t)rOrig * 128 + kk]
                             : W_hh[(size_t)rOrig * 256 + (kk - 128)];
        Bp[idx] = (f16)w;
    }
    if (idx < 512) {
        int by = idx >> 6, c = idx & 63;
        int g = c >> 4, jl = c & 15;
        int rOrig = g * 256 + by * 16 + jl;
        biasP[idx] = b_ih[rOrig] + b_hh[rOrig];
    }
    if (idx < 18 * 512) flags[idx] = 0u;
}

// One A fragment: 8 fp16 of row `row`, k = kci*32 + kq*8 .. +8.
// embL is the level's fp32 slice base (row-relative); h_in the child h.
__device__ __forceinline__ f16x8 loadAfr(
    const float* __restrict__ embL, const f16* __restrict__ h_in,
    int row, int kci, int kq)
{
    if (kci < 4) {
        const float* p = embL + (size_t)row * 128 + kci * 32 + kq * 8;
        float4 a = *(const float4*)p;
        float4 b = *(const float4*)(p + 4);
        f16x8 r;
        r[0] = (f16)a.x; r[1] = (f16)a.y; r[2] = (f16)a.z; r[3] = (f16)a.w;
        r[4] = (f16)b.x; r[5] = (f16)b.y; r[6] = (f16)b.z; r[7] = (f16)b.w;
        return r;
    }
    return *(const f16x8*)(h_in + (size_t)row * 256 + (kci - 4) * 32 + kq * 8);
}

// Compute + store one 256-row tile slice (this wave: 64 rows x 64 packed cols).
template <int NCH>
__device__ __forceinline__ void do_tile(
    const float* __restrict__ embL, const f16* __restrict__ h_in,
    const float* __restrict__ c_in, f16* __restrict__ h_out,
    float* __restrict__ c_out, float* __restrict__ root,
    const f16* __restrict__ Bs, int n, int row0, int l15, int kq,
    int j, float bi, float bfv, float bg, float bo)
{
    int rowm[4];
    #pragma unroll
    for (int mi = 0; mi < 4; ++mi) {
        int r = row0 + mi * 16 + l15;
        rowm[mi] = (r < n) ? r : (n - 1);
    }

    f32x4 acc[4][4];
    #pragma unroll
    for (int a = 0; a < 4; ++a)
        #pragma unroll
        for (int b = 0; b < 4; ++b) acc[a][b] = (f32x4)0.f;

    f16x8 af[3][4];
    #pragma unroll
    for (int pk = 0; pk < 3; ++pk)
        if (pk < NCH) {
            #pragma unroll
            for (int mi = 0; mi < 4; ++mi)
                af[pk][mi] = loadAfr(embL, h_in, rowm[mi], pk, kq);
        }

    #pragma unroll
    for (int kci = 0; kci < NCH; ++kci) {
        const int sl = kci % 3;
        f16x8 bf[4];
        #pragma unroll
        for (int g = 0; g < 4; ++g)
            bf[g] = *(const f16x8*)&Bs[((kci * 4 + kq) * 64 + g * 16 + l15) * 8];
        f16x8 a0 = af[sl][0], a1 = af[sl][1], a2 = af[sl][2], a3 = af[sl][3];
        if (kci + 3 < NCH) {
            #pragma unroll
            for (int mi = 0; mi < 4; ++mi)
                af[sl][mi] = loadAfr(embL, h_in, rowm[mi], kci + 3, kq);
        }
        #pragma unroll
        for (int g = 0; g < 4; ++g) {
            acc[0][g] = __builtin_amdgcn_mfma_f32_16x16x32_f16(a0, bf[g], acc[0][g], 0, 0, 0);
            acc[1][g] = __builtin_amdgcn_mfma_f32_16x16x32_f16(a1, bf[g], acc[1][g], 0, 0, 0);
            acc[2][g] = __builtin_amdgcn_mfma_f32_16x16x32_f16(a2, bf[g], acc[2][g], 0, 0, 0);
            acc[3][g] = __builtin_amdgcn_mfma_f32_16x16x32_f16(a3, bf[g], acc[3][g], 0, 0, 0);
        }
    }

    #pragma unroll
    for (int mi = 0; mi < 4; ++mi) {
        #pragma unroll
        for (int r = 0; r < 4; ++r) {
            int row = row0 + mi * 16 + kq * 4 + r;
            if (row < n) {
                float gi = acc[mi][0][r] + bi;
                float gf = acc[mi][1][r] + bfv;
                float gg = acc[mi][2][r] + bg;
                float go = acc[mi][3][r] + bo;
                float cl = (NCH == 4) ? 0.f : c_in[(size_t)row * 128 + j];
                float cn = sigf(gf) * cl + sigf(gi) * tanh_fast(gg);
                float hn = sigf(go) * tanh_fast(cn);
                if (root) {
                    root[j] = hn;
                    root[128 + j] = cn;
                } else {
                    h_out[(size_t)row * 128 + j] = (f16)hn;
                    if (!(row & 1))
                        c_out[(size_t)(row >> 1) * 128 + j] = cn;
                }
            }
        }
    }
}

__global__ __launch_bounds__(256, 3) void mega(
    const float* __restrict__ emb, const f16* __restrict__ Bp,
    const float* __restrict__ biasP, f16* __restrict__ hbase,
    float* __restrict__ cbase, float* __restrict__ root,
    unsigned* __restrict__ flags)
{
    __shared__ __align__(16) f16 Bs[24576];   // 48 KB: this block's by-slice

    const int tid = threadIdx.x;
    const int lane = tid & 63;
    const int w = tid >> 6;
    const int bid = blockIdx.x;
    const int by = bid & 7;
    const int stripe = bid >> 3;          // 0..95
    const int l15 = lane & 15;
    const int kq = lane >> 4;
    const int j = by * 16 + l15;

    {   // B slice -> LDS once for the whole kernel
        const char* gB = (const char*)(Bp + (size_t)by * 24576);
        char* lB = (char*)Bs;
        #pragma unroll
        for (int i = 0; i < 12; ++i)
            load_lds_16(gB + ((size_t)(i * 256 + tid)) * 16,
                        lB + ((size_t)(i * 256 + w * 64)) * 16);
    }
    const float bi  = biasP[by * 64 + 0 + l15];
    const float bfv = biasP[by * 64 + 16 + l15];
    const float bg  = biasP[by * 64 + 32 + l15];
    const float bo  = biasP[by * 64 + 48 + l15];
    __syncthreads();   // B resident (implicit vmcnt drain before barrier)

    // ---- level 17 (no deps, emb-only K=128) ----
    {
        const int n = 1 << 17;
        const float* embL = emb + (size_t)(n - 1) * 128;
        for (int rb = stripe; rb < 512; rb += NSTRIPE) {
            int row0 = rb * 256 + w * 64;
            do_tile<4>(embL, (const f16*)nullptr, (const float*)nullptr,
                       hbase, cbase, nullptr, Bs, n, row0, l15, kq,
                       j, bi, bfv, bg, bo);
            __syncthreads();
            if (tid == 0) {
                __threadfence();
                __hip_atomic_fetch_add(&flags[17 * 512 + rb], 1u,
                                       __ATOMIC_ACQ_REL, __HIP_MEMORY_SCOPE_AGENT);
            }
        }
    }

    // ---- levels 16..0 ----
    for (int dd = 16; dd >= 0; --dd) {
        const int n = 1 << dd;
        int G = n >> 8; if (G == 0) G = 1;
        int Gc = (n << 1) >> 8; if (Gc == 0) Gc = 1;
        const f16*   h_in  = hbase + ((size_t)(1 << 18) - ((size_t)1 << (dd + 2))) * 128;
        const float* c_in  = cbase + ((size_t)(1 << 17) - ((size_t)1 << (dd + 1))) * 128;
        f16*   h_out = hbase + ((size_t)(1 << 18) - ((size_t)1 << (dd + 1))) * 128;
        float* c_out = cbase + ((size_t)(1 << 17) - ((size_t)1 << dd)) * 128;
        const float* embL = emb + (size_t)(n - 1) * 128;
        float* rt = (dd == 0) ? root : nullptr;

        for (int rb = stripe; rb < G; rb += NSTRIPE) {
            int g0 = 2 * rb;     if (g0 > Gc - 1) g0 = Gc - 1;
            int g1 = 2 * rb + 1; if (g1 > Gc - 1) g1 = Gc - 1;
            if (tid == 0) {
                while (__hip_atomic_load(&flags[(dd + 1) * 512 + g0],
                        __ATOMIC_ACQUIRE, __HIP_MEMORY_SCOPE_AGENT) < 8u)
                    __builtin_amdgcn_s_sleep(2);
                while (__hip_atomic_load(&flags[(dd + 1) * 512 + g1],
                        __ATOMIC_ACQUIRE, __HIP_MEMORY_SCOPE_AGENT) < 8u)
                    __builtin_amdgcn_s_sleep(2);
                __threadfence();
            }
            __syncthreads();   // deps ready for all 4 waves

            int row0 = rb * 256 + w * 64;
            do_tile<12>(embL, h_in, c_in, h_out, c_out, rt, Bs,
                        n, row0, l15, kq, j, bi, bfv, bg, bo);
            __syncthreads();
            if (tid == 0) {
                __threadfence();
                __hip_atomic_fetch_add(&flags[dd * 512 + rb], 1u,
                                       __ATOMIC_ACQ_REL, __HIP_MEMORY_SCOPE_AGENT);
            }
        }
    }
}

extern "C" void kernel_launch(void* const* d_in, const int* in_sizes, int n_in,
                              void* d_out, int out_size, void* d_ws, size_t ws_size,
                              hipStream_t stream) {
    const float* emb  = (const float*)d_in[0];
    const float* W_ih = (const float*)d_in[1];
    const float* W_hh = (const float*)d_in[2];
    const float* b_ih = (const float*)d_in[3];
    const float* b_hh = (const float*)d_in[4];

    char* wsb = (char*)d_ws;
    f16*      Bp    = (f16*)wsb;                   // 393216 B
    float*    biasP = (float*)(wsb + 393216);      // 2048 B
    unsigned* flags = (unsigned*)(wsb + 397312);   // 18*512*4 = 36864 B
    f16*   hbase = (f16*)(wsb + 1048576);                 // 2^18*128 f16 = 64 MiB
    float* cbase = (float*)(wsb + 1048576 + 67108864);    // 2^17*128 f32 = 64 MiB
    if (ws_size < 1048576 + 2 * 67108864) return;

    pack_weights<<<768, 256, 0, stream>>>(W_ih, W_hh, b_ih, b_hh, Bp, biasP, flags);
    mega<<<768, 256, 0, stream>>>(emb, Bp, biasP, hbase, cbase,
                                  (float*)d_out, flags);
}

// Round 8
// 998.183 us; speedup vs baseline: 1.5282x; 1.5282x over previous
//
#include <hip/hip_runtime.h>

// BinaryTreeLSTM — round 8: per-level launches (round-6 structure) with
// grid-stride B-resident blocks, in-kernel emb cvt, 64-block merged tail.
//  * B (384x512 fp16) pre-packed in 8 gate-major 64-col slices of 48 KB;
//    each block DMAs its slice to LDS ONCE PER LEVEL, then grid-strides over
//    256-row tiles (round 6 re-staged B per tile: 2048 blocks x 48 KB at d16).
//  * A fragments global->register, ring depth 3, fully unrolled (template
//    NCH). emb read fp32 + in-register cvt (cvt pass deleted: 134 MB read
//    beats 201 MB cvt + 67 MB fp16 re-read, and one less launch).
//  * h fp16 per-level regions, c fp32 packed even rows (left children only).
//  * Tail d=9..0 in one 64-block kernel with a counter grid-barrier
//    (counter zeroed by pack_weights; 64 pollers only — round 7's 768-block
//    per-tile flag polling cost ~500 MB of HBM fetches and 3x time).
//  * Round-7 lesson: dataflow flags at tile granularity lose to launches.

typedef _Float16 f16;
typedef f16 f16x8 __attribute__((ext_vector_type(8)));
typedef float f32x4 __attribute__((ext_vector_type(4)));

#define LOG2E 1.44269504f

__device__ __forceinline__ float sigf(float x) {
    return __builtin_amdgcn_rcpf(1.f + __builtin_amdgcn_exp2f(-x * LOG2E));
}
__device__ __forceinline__ float tanh_fast(float x) {
    return 1.f - 2.f * __builtin_amdgcn_rcpf(1.f + __builtin_amdgcn_exp2f(2.f * x * LOG2E));
}

__device__ __forceinline__ void load_lds_16(const void* g, void* l) {
    __builtin_amdgcn_global_load_lds(
        (const __attribute__((address_space(1))) unsigned int*)g,
        (__attribute__((address_space(3))) unsigned int*)l, 16, 0, 0);
}

// Bp layout: [by(8)][kci(12)][kq(4)][c(64)][k8(8)] fp16, c = g*16 + jl,
// orig row = g*256 + by*16 + jl, orig k = kci*32 + kq*8 + k8.
// Also zeroes the tail barrier counter (ws is 0xAA-poisoned every call).
__global__ __launch_bounds__(256) void pack_weights(
    const float* __restrict__ W_ih, const float* __restrict__ W_hh,
    const float* __restrict__ b_ih, const float* __restrict__ b_hh,
    f16* __restrict__ Bp, float* __restrict__ biasP, unsigned* __restrict__ barc)
{
    int idx = blockIdx.x * 256 + threadIdx.x;
    if (idx < 196608) {
        int by = idx / 24576;
        int r = idx - by * 24576;
        int kci = r / 2048;
        int r2 = r & 2047;
        int kq = r2 >> 9;
        int r3 = r2 & 511;
        int c = r3 >> 3;
        int k8 = r3 & 7;
        int g = c >> 4, jl = c & 15;
        int rOrig = g * 256 + by * 16 + jl;
        int kk = kci * 32 + kq * 8 + k8;
        float w = (kk < 128) ? W_ih[(size_t)rOrig * 128 + kk]
                             : W_hh[(size_t)rOrig * 256 + (kk - 128)];
        Bp[idx] = (f16)w;
    }
    if (idx < 512) {
        int by = idx >> 6, c = idx & 63;
        int g = c >> 4, jl = c & 15;
        int rOrig = g * 256 + by * 16 + jl;
        biasP[idx] = b_ih[rOrig] + b_hh[rOrig];
    }
    if (idx < 16) barc[idx] = 0u;
}

// One A fragment: 8 fp16 of row `row`, k = kci*32 + kq*8 .. +8.
__device__ __forceinline__ f16x8 loadAfr(
    const float* __restrict__ embL, const f16* __restrict__ h_in,
    int row, int kci, int kq)
{
    if (kci < 4) {
        const float* p = embL + (size_t)row * 128 + kci * 32 + kq * 8;
        float4 a = *(const float4*)p;
        float4 b = *(const float4*)(p + 4);
        f16x8 r;
        r[0] = (f16)a.x; r[1] = (f16)a.y; r[2] = (f16)a.z; r[3] = (f16)a.w;
        r[4] = (f16)b.x; r[5] = (f16)b.y; r[6] = (f16)b.z; r[7] = (f16)b.w;
        return r;
    }
    return *(const f16x8*)(h_in + (size_t)row * 256 + (kci - 4) * 32 + kq * 8);
}

// Compute + store one 256-row tile slice (this wave: 64 rows x 64 packed cols).
template <int NCH>
__device__ __forceinline__ void do_tile(
    const float* __restrict__ embL, const f16* __restrict__ h_in,
    const float* __restrict__ c_in, f16* __restrict__ h_out,
    float* __restrict__ c_out, float* __restrict__ root,
    const f16* __restrict__ Bs, int n, int row0, int l15, int kq,
    int j, float bi, float bfv, float bg, float bo)
{
    int rowm[4];
    #pragma unroll
    for (int mi = 0; mi < 4; ++mi) {
        int r = row0 + mi * 16 + l15;
        rowm[mi] = (r < n) ? r : (n - 1);
    }

    f32x4 acc[4][4];
    #pragma unroll
    for (int a = 0; a < 4; ++a)
        #pragma unroll
        for (int b = 0; b < 4; ++b) acc[a][b] = (f32x4)0.f;

    f16x8 af[3][4];
    #pragma unroll
    for (int pk = 0; pk < 3; ++pk)
        if (pk < NCH) {
            #pragma unroll
            for (int mi = 0; mi < 4; ++mi)
                af[pk][mi] = loadAfr(embL, h_in, rowm[mi], pk, kq);
        }

    #pragma unroll
    for (int kci = 0; kci < NCH; ++kci) {
        const int sl = kci % 3;
        f16x8 bf[4];
        #pragma unroll
        for (int g = 0; g < 4; ++g)
            bf[g] = *(const f16x8*)&Bs[((kci * 4 + kq) * 64 + g * 16 + l15) * 8];
        f16x8 a0 = af[sl][0], a1 = af[sl][1], a2 = af[sl][2], a3 = af[sl][3];
        if (kci + 3 < NCH) {
            #pragma unroll
            for (int mi = 0; mi < 4; ++mi)
                af[sl][mi] = loadAfr(embL, h_in, rowm[mi], kci + 3, kq);
        }
        #pragma unroll
        for (int g = 0; g < 4; ++g) {
            acc[0][g] = __builtin_amdgcn_mfma_f32_16x16x32_f16(a0, bf[g], acc[0][g], 0, 0, 0);
            acc[1][g] = __builtin_amdgcn_mfma_f32_16x16x32_f16(a1, bf[g], acc[1][g], 0, 0, 0);
            acc[2][g] = __builtin_amdgcn_mfma_f32_16x16x32_f16(a2, bf[g], acc[2][g], 0, 0, 0);
            acc[3][g] = __builtin_amdgcn_mfma_f32_16x16x32_f16(a3, bf[g], acc[3][g], 0, 0, 0);
        }
    }

    #pragma unroll
    for (int mi = 0; mi < 4; ++mi) {
        #pragma unroll
        for (int r = 0; r < 4; ++r) {
            int row = row0 + mi * 16 + kq * 4 + r;
            if (row < n) {
                float gi = acc[mi][0][r] + bi;
                float gf = acc[mi][1][r] + bfv;
                float gg = acc[mi][2][r] + bg;
                float go = acc[mi][3][r] + bo;
                float cl = (NCH == 4) ? 0.f : c_in[(size_t)row * 128 + j];
                float cn = sigf(gf) * cl + sigf(gi) * tanh_fast(gg);
                float hn = sigf(go) * tanh_fast(cn);
                if (root) {
                    root[j] = hn;
                    root[128 + j] = cn;
                } else {
                    h_out[(size_t)row * 128 + j] = (f16)hn;
                    if (!(row & 1))
                        c_out[(size_t)(row >> 1) * 128 + j] = cn;
                }
            }
        }
    }
}

// Big levels: grid = 8 * S blocks; block (by = bid&7, s0 = bid>>3) loads B
// once, grid-strides rb = s0, s0+S, ... over the n/256 row tiles.
template <int NCH>
__global__ __launch_bounds__(256, 3) void level_big(
    const float* __restrict__ emb,
    const f16* __restrict__ Bp, const float* __restrict__ biasP,
    const f16* __restrict__ h_in,    // (n,256) fp16 child h
    const float* __restrict__ c_in,  // (n,128) fp32 packed left-child c
    f16* __restrict__ h_out,         // (n,128) fp16
    float* __restrict__ c_out,       // (n/2,128) fp32 packed even rows
    int n)
{
    __shared__ __align__(16) f16 Bs[24576];   // 48 KB

    const int tid = threadIdx.x;
    const int lane = tid & 63;
    const int w = tid >> 6;
    const int by = blockIdx.x & 7;
    const int s0 = blockIdx.x >> 3;
    const int S = gridDim.x >> 3;
    const int l15 = lane & 15;
    const int kq = lane >> 4;
    const int j = by * 16 + l15;

    {   // B slice -> LDS once per level
        const char* gB = (const char*)(Bp + (size_t)by * 24576);
        char* lB = (char*)Bs;
        #pragma unroll
        for (int i = 0; i < 12; ++i)
            load_lds_16(gB + ((size_t)(i * 256 + tid)) * 16,
                        lB + ((size_t)(i * 256 + w * 64)) * 16);
    }
    const float bi  = biasP[by * 64 + 0 + l15];
    const float bfv = biasP[by * 64 + 16 + l15];
    const float bg  = biasP[by * 64 + 32 + l15];
    const float bo  = biasP[by * 64 + 48 + l15];
    const float* embL = emb + (size_t)(n - 1) * 128;
    __syncthreads();   // B resident; only barrier

    const int G = n >> 8;
    for (int rb = s0; rb < G; rb += S) {
        int row0 = rb * 256 + w * 64;
        do_tile<NCH>(embL, h_in, c_in, h_out, c_out, nullptr, Bs,
                     n, row0, l15, kq, j, bi, bfv, bg, bo);
    }
}

// Tail: levels d=9..0, 64 blocks (by = bid&7, s = bid>>3), counter barrier.
__global__ __launch_bounds__(256, 3) void levels_tail(
    const float* __restrict__ emb,
    const f16* __restrict__ Bp, const float* __restrict__ biasP,
    f16* __restrict__ hbase, float* __restrict__ cbase,
    float* __restrict__ root, unsigned* __restrict__ barc)
{
    __shared__ __align__(16) f16 Bs[24576];

    const int tid = threadIdx.x;
    const int lane = tid & 63;
    const int w = tid >> 6;
    const int by = blockIdx.x & 7;
    const int s = blockIdx.x >> 3;   // 0..7
    const int l15 = lane & 15;
    const int kq = lane >> 4;
    const int j = by * 16 + l15;

    {   // B slice -> LDS once
        const char* gB = (const char*)(Bp + (size_t)by * 24576);
        char* lB = (char*)Bs;
        #pragma unroll
        for (int i = 0; i < 12; ++i)
            load_lds_16(gB + ((size_t)(i * 256 + tid)) * 16,
                        lB + ((size_t)(i * 256 + w * 64)) * 16);
    }
    const float bi  = biasP[by * 64 + 0 + l15];
    const float bfv = biasP[by * 64 + 16 + l15];
    const float bg  = biasP[by * 64 + 32 + l15];
    const float bo  = biasP[by * 64 + 48 + l15];
    __syncthreads();

    unsigned phase = 0;
    for (int dd = 9; dd >= 0; --dd) {
        const int n = 1 << dd;
        int G = n >> 8; if (G == 0) G = 1;
        const f16*   h_in  = hbase + ((size_t)(1 << 18) - ((size_t)1 << (dd + 2))) * 128;
        const float* c_in  = cbase + ((size_t)(1 << 17) - ((size_t)1 << (dd + 1))) * 128;
        f16*   h_out = hbase + ((size_t)(1 << 18) - ((size_t)1 << (dd + 1))) * 128;
        float* c_out = cbase + ((size_t)(1 << 17) - ((size_t)1 << dd)) * 128;
        const float* embL = emb + (size_t)(n - 1) * 128;
        float* rt = (dd == 0) ? root : nullptr;

        if (s < G) {
            int row0 = s * 256 + w * 64;
            do_tile<12>(embL, h_in, c_in, h_out, c_out, rt, Bs,
                        n, row0, l15, kq, j, bi, bfv, bg, bo);
        }

        if (dd > 0) {   // 64-block barrier
            ++phase;
            __syncthreads();
            if (tid == 0) {
                __threadfence();
                __hip_atomic_fetch_add(barc, 1u, __ATOMIC_ACQ_REL,
                                       __HIP_MEMORY_SCOPE_AGENT);
                while (__hip_atomic_load(barc, __ATOMIC_ACQUIRE,
                        __HIP_MEMORY_SCOPE_AGENT) < 64u * phase)
                    __builtin_amdgcn_s_sleep(8);
                __threadfence();
            }
            __syncthreads();
        }
    }
}

extern "C" void kernel_launch(void* const* d_in, const int* in_sizes, int n_in,
                              void* d_out, int out_size, void* d_ws, size_t ws_size,
                              hipStream_t stream) {
    const float* emb  = (const float*)d_in[0];
    const float* W_ih = (const float*)d_in[1];
    const float* W_hh = (const float*)d_in[2];
    const float* b_ih = (const float*)d_in[3];
    const float* b_hh = (const float*)d_in[4];

    char* wsb = (char*)d_ws;
    f16*      Bp    = (f16*)wsb;                   // 393216 B
    float*    biasP = (float*)(wsb + 393216);      // 2048 B
    unsigned* barc  = (unsigned*)(wsb + 397312);   // 64 B
    f16*   hbase = (f16*)(wsb + 1048576);                 // 2^18*128 f16 = 64 MiB
    float* cbase = (float*)(wsb + 1048576 + 67108864);    // 2^17*128 f32 = 64 MiB
    if (ws_size < 1048576 + 2 * 67108864) return;

    pack_weights<<<768, 256, 0, stream>>>(W_ih, W_hh, b_ih, b_hh, Bp, biasP, barc);

    // Level dd regions: h at hbase + (2^18 - 2^(dd+1))*128 (fp16, 2^dd x 128),
    //                   c at cbase + (2^17 - 2^dd)*128 (fp32 packed, 2^(dd-1) x 128).
    for (int dd = 17; dd >= 10; --dd) {
        int n = 1 << dd;
        int G = n >> 8;
        int S = (G < 96) ? G : 96;
        dim3 grid(8 * S);
        const f16*   hin  = (const f16*)(hbase + ((size_t)(1 << 18) - ((size_t)1 << (dd + 2))) * 128);
        const float* cin  = (const float*)(cbase + ((size_t)(1 << 17) - ((size_t)1 << (dd + 1))) * 128);
        f16*   hout = hbase + ((size_t)(1 << 18) - ((size_t)1 << (dd + 1))) * 128;
        float* cout = cbase + ((size_t)(1 << 17) - ((size_t)1 << dd)) * 128;
        if (dd == 17)
            level_big<4><<<grid, 256, 0, stream>>>(emb, Bp, biasP,
                nullptr, nullptr, hout, cout, n);
        else
            level_big<12><<<grid, 256, 0, stream>>>(emb, Bp, biasP,
                hin, cin, hout, cout, n);
    }

    levels_tail<<<64, 256, 0, stream>>>(emb, Bp, biasP, hbase, cbase,
                                        (float*)d_out, barc);
}